// Round 1
// baseline (1639.713 us; speedup 1.0000x reference)
//
#include <hip/hip_runtime.h>

#define N_   32
#define C_   512
#define HW_  3136
#define W_   56
#define H_   56
#define CM_  128
#define P_   512
#define KK_  9

// ---------------- pool: pooled[n,c] = mean(x[n,c,:,:]) ----------------
__global__ __launch_bounds__(256) void pool_kernel(const float* __restrict__ x,
                                                   float* __restrict__ pooled) {
    int nc = blockIdx.x;                     // n*C + c
    const float* p = x + (size_t)nc * HW_;
    float s = 0.f;
    for (int i = threadIdx.x; i < HW_; i += 256) s += p[i];
    for (int off = 32; off; off >>= 1) s += __shfl_down(s, off, 64);
    __shared__ float ws[4];
    if ((threadIdx.x & 63) == 0) ws[threadIdx.x >> 6] = s;
    __syncthreads();
    if (threadIdx.x == 0)
        pooled[nc] = (ws[0] + ws[1] + ws[2] + ws[3]) * (1.0f / HW_);
}

// ---------------- g[n,o] = relu(pooled[n,:] @ conv_w[o,:] + conv_b[o]) ----------------
__global__ __launch_bounds__(128) void g_kernel(const float* __restrict__ pooled,
                                                const float* __restrict__ conv_w,
                                                const float* __restrict__ conv_b,
                                                float* __restrict__ g) {
    int n = blockIdx.x, o = threadIdx.x;     // 128 threads
    __shared__ float ps[C_];
    for (int c = threadIdx.x; c < C_; c += 128) ps[c] = pooled[n * C_ + c];
    __syncthreads();
    float acc = conv_b[o];
    for (int c = 0; c < C_; c++) acc += ps[c] * conv_w[o * C_ + c];
    g[n * CM_ + o] = fmaxf(acc, 0.f);
}

// ---------------- Wk[n,oc,ic,kk] = relu(ckk_w[oc]*(ck_w[kk]*g[n,ic]+ck_b[kk]) + ckk_b[oc]) ----
__global__ __launch_bounds__(256) void wk_kernel(const float* __restrict__ g,
                                                 const float* __restrict__ ck_w,
                                                 const float* __restrict__ ck_b,
                                                 const float* __restrict__ ckk_w,
                                                 const float* __restrict__ ckk_b,
                                                 float* __restrict__ Wk) {
    int idx = blockIdx.x * 256 + threadIdx.x;
    if (idx >= N_ * CM_ * CM_ * KK_) return;
    int kk = idx % KK_;
    int ic = (idx / KK_) % CM_;
    int oc = (idx / (KK_ * CM_)) % CM_;
    int n  = idx / (KK_ * CM_ * CM_);
    float ker = ck_w[kk] * g[n * CM_ + ic] + ck_b[kk];
    Wk[idx] = fmaxf(ckk_w[oc] * ker + ckk_b[oc], 0.f);
}

// ---------------- per-pixel 1x1 GEMM: out[n,oc,pix] = act(sum_c in[n,c,pix]*w[oc,c] + b[oc]) ----
// grid: (HW/64, Cout/64, N), block 256. Tile 64 pix x 64 oc, thread microtile 4x4.
__global__ __launch_bounds__(256) void pix_gemm(const float* __restrict__ in,
                                                const float* __restrict__ w,
                                                const float* __restrict__ b,
                                                float* __restrict__ out,
                                                int Cin, int Cout, int relu) {
    int pixbase = blockIdx.x * 64;
    int ocbase  = blockIdx.y * 64;
    int n       = blockIdx.z;
    int t = threadIdx.x;
    int p = t & 15, q = t >> 4;              // p: pixel quad, q: oc quad
    __shared__ float xs[32 * 64];            // [c][pix]
    __shared__ float wsh[64 * 33];           // [oc][c] pad 33
    float acc[4][4] = {};                    // [pixsub][ocsub]
    const float* inb = in + (size_t)n * Cin * HW_ + pixbase;
    for (int c0 = 0; c0 < Cin; c0 += 32) {
        for (int i = 0; i < 8; i++) {
            int idx = i * 256 + t;
            int c = idx >> 6, pix = idx & 63;
            xs[idx] = inb[(size_t)(c0 + c) * HW_ + pix];
        }
        for (int i = 0; i < 8; i++) {
            int idx = i * 256 + t;
            int o = idx >> 5, c = idx & 31;
            wsh[o * 33 + c] = w[(size_t)(ocbase + o) * Cin + c0 + c];
        }
        __syncthreads();
        #pragma unroll
        for (int kk = 0; kk < 32; kk++) {
            float4 xv = *(const float4*)&xs[kk * 64 + p * 4];
            #pragma unroll
            for (int j = 0; j < 4; j++) {
                float wv = wsh[(q * 4 + j) * 33 + kk];
                acc[0][j] += xv.x * wv;
                acc[1][j] += xv.y * wv;
                acc[2][j] += xv.z * wv;
                acc[3][j] += xv.w * wv;
            }
        }
        __syncthreads();
    }
    #pragma unroll
    for (int j = 0; j < 4; j++) {
        int oc = ocbase + q * 4 + j;
        float bias = b[oc];
        float4 r;
        r.x = acc[0][j] + bias;
        r.y = acc[1][j] + bias;
        r.z = acc[2][j] + bias;
        r.w = acc[3][j] + bias;
        if (relu) {
            r.x = fmaxf(r.x, 0.f); r.y = fmaxf(r.y, 0.f);
            r.z = fmaxf(r.z, 0.f); r.w = fmaxf(r.w, 0.f);
        }
        *(float4*)&out[((size_t)n * Cout + oc) * HW_ + pixbase + p * 4] = r;
    }
}

// ---------------- dynamic 3x3 conv: y[n,oc,h,w] = adap_b[oc] + sum_{ic,kk} Wk[n,oc,ic,kk]*f_pad ----
// grid: (49, 2, 32), block 256. Tile 64 pix x 64 oc, ic chunked by 8.
__global__ __launch_bounds__(256) void dyn_conv(const float* __restrict__ f,
                                                const float* __restrict__ Wk,
                                                const float* __restrict__ adap_b,
                                                float* __restrict__ y) {
    int pixbase = blockIdx.x * 64;
    int ocbase  = blockIdx.y * 64;
    int n       = blockIdx.z;
    int t = threadIdx.x;
    int p = t & 15, q = t >> 4;
    int h0 = pixbase / W_;
    __shared__ float fsh[8 * 5 * 58];        // [ic8][row(h0-1..h0+3)][col(-1..56)]
    __shared__ float wksh[8 * 64 * 12];      // [ic8][oc][kk pad 12]
    float acc[4][4];
    int hh[4], ww[4];
    #pragma unroll
    for (int ii = 0; ii < 4; ii++) {
        int gp = pixbase + p * 4 + ii;
        hh[ii] = gp / W_ - (h0 - 1);         // staged row index of output row
        ww[ii] = gp % W_;
    }
    #pragma unroll
    for (int j = 0; j < 4; j++) {
        float ab = adap_b[ocbase + q * 4 + j];
        #pragma unroll
        for (int ii = 0; ii < 4; ii++) acc[ii][j] = ab;
    }
    for (int ic0 = 0; ic0 < CM_; ic0 += 8) {
        for (int idx = t; idx < 8 * 5 * 58; idx += 256) {
            int i = idx / 290, rem = idx % 290;
            int r = rem / 58, col = rem % 58;
            int h = h0 - 1 + r, wv = col - 1;
            float v = 0.f;
            if (h >= 0 && h < H_ && wv >= 0 && wv < W_)
                v = f[((size_t)n * CM_ + ic0 + i) * HW_ + h * W_ + wv];
            fsh[idx] = v;
        }
        for (int idx = t; idx < 8 * 64 * KK_; idx += 256) {
            int oc = idx / 72, rem = idx % 72;
            int i = rem / KK_, kk = rem % KK_;
            wksh[(i * 64 + oc) * 12 + kk] =
                Wk[(((size_t)n * CM_ + ocbase + oc) * CM_ + ic0 + i) * KK_ + kk];
        }
        __syncthreads();
        #pragma unroll
        for (int i = 0; i < 8; i++) {
            float fv[4][9];
            const float* fb = &fsh[i * 290];
            #pragma unroll
            for (int ii = 0; ii < 4; ii++)
                #pragma unroll
                for (int dh = 0; dh < 3; dh++)
                    #pragma unroll
                    for (int dw = 0; dw < 3; dw++)
                        fv[ii][dh * 3 + dw] = fb[(hh[ii] + dh - 1) * 58 + ww[ii] + dw];
            #pragma unroll
            for (int j = 0; j < 4; j++) {
                const float* wkb = &wksh[(i * 64 + q * 4 + j) * 12];
                #pragma unroll
                for (int kk = 0; kk < 9; kk++) {
                    float wv = wkb[kk];
                    #pragma unroll
                    for (int ii = 0; ii < 4; ii++) acc[ii][j] += wv * fv[ii][kk];
                }
            }
        }
        __syncthreads();
    }
    #pragma unroll
    for (int j = 0; j < 4; j++) {
        float4 r = {acc[0][j], acc[1][j], acc[2][j], acc[3][j]};
        *(float4*)&y[((size_t)n * CM_ + ocbase + q * 4 + j) * HW_ + pixbase + p * 4] = r;
    }
}

extern "C" void kernel_launch(void* const* d_in, const int* in_sizes, int n_in,
                              void* d_out, int out_size, void* d_ws, size_t ws_size,
                              hipStream_t stream) {
    const float* x      = (const float*)d_in[0];
    const float* conv_w = (const float*)d_in[1];
    const float* conv_b = (const float*)d_in[2];
    const float* ck_w   = (const float*)d_in[3];
    const float* ck_b   = (const float*)d_in[4];
    const float* ckk_w  = (const float*)d_in[5];
    const float* ckk_b  = (const float*)d_in[6];
    const float* adap_b = (const float*)d_in[7];
    const float* fuse_w = (const float*)d_in[8];
    const float* fuse_b = (const float*)d_in[9];
    float* out = (float*)d_out;

    float* ws     = (float*)d_ws;
    float* pooled = ws;                         // 16384
    float* g      = pooled + N_ * C_;           // 4096
    float* Wk     = g + N_ * CM_;               // 4718592
    float* f      = Wk + (size_t)N_ * CM_ * CM_ * KK_;   // 12845056
    float* y      = f + (size_t)N_ * CM_ * HW_;          // 12845056

    pool_kernel<<<N_ * C_, 256, 0, stream>>>(x, pooled);
    g_kernel<<<N_, 128, 0, stream>>>(pooled, conv_w, conv_b, g);
    int wk_total = N_ * CM_ * CM_ * KK_;
    wk_kernel<<<(wk_total + 255) / 256, 256, 0, stream>>>(g, ck_w, ck_b, ckk_w, ckk_b, Wk);
    pix_gemm<<<dim3(HW_ / 64, CM_ / 64, N_), 256, 0, stream>>>(x, conv_w, conv_b, f, C_, CM_, 1);
    dyn_conv<<<dim3(HW_ / 64, CM_ / 64, N_), 256, 0, stream>>>(f, Wk, adap_b, y);
    pix_gemm<<<dim3(HW_ / 64, P_ / 64, N_), 256, 0, stream>>>(y, fuse_w, fuse_b, out, CM_, P_, 0);
}

// Round 2
// 514.753 us; speedup vs baseline: 3.1854x; 3.1854x over previous
//
#include <hip/hip_runtime.h>

#define N_   32
#define C_   512
#define HW_  3136
#define W_   56
#define H_   56
#define CM_  128
#define P_   512

typedef __attribute__((ext_vector_type(8))) short bf16x8;
typedef __attribute__((ext_vector_type(4))) float f32x4;

__device__ inline ushort f2bf(float x) {
    unsigned u = __float_as_uint(x);
    u += 0x7fff + ((u >> 16) & 1);
    return (ushort)(u >> 16);
}

// ---- prep: pack conv_w / fuse_w into A-fragment layouts ----
// Acv[(cblk*128 + cm)*8 + ci]  (cblk = c/8, 64 blocks)
// Afu[(kb*512 + p)*8 + ci]     (kb = cm/8, 16 blocks)
__global__ __launch_bounds__(256) void prep_w(const float* __restrict__ conv_w,
                                              const float* __restrict__ fuse_w,
                                              ushort* __restrict__ Acv,
                                              ushort* __restrict__ Afu) {
    int idx = blockIdx.x * 256 + threadIdx.x;   // < 131072
    if (idx < 65536) {
        int ci = idx & 7, cm = (idx >> 3) & 127, cb = idx >> 10;
        Acv[idx] = f2bf(conv_w[cm * C_ + cb * 8 + ci]);
    } else {
        int j = idx - 65536;
        int ci = j & 7, p = (j >> 3) & 511, kb = j >> 12;
        Afu[j] = f2bf(fuse_w[p * CM_ + kb * 8 + ci]);
    }
}

// ---- transpose+cast x: [n][c][pix] f32 -> x_t [n][pix][512] bf16, plus pooled sums ----
__global__ __launch_bounds__(256) void transpose_cast(const float* __restrict__ x,
                                                      ushort* __restrict__ x_t,
                                                      float* __restrict__ pooled) {
    int pixbase = blockIdx.x * 64, c0 = blockIdx.y * 64, n = blockIdx.z;
    __shared__ float tile[64 * 65];
    int t = threadIdx.x;
    const float inv = 1.0f / (float)HW_;
    #pragma unroll
    for (int it = 0; it < 4; it++) {
        int c = it * 16 + (t >> 4), p4 = (t & 15) * 4;
        float4 v = *(const float4*)&x[((size_t)(n * C_ + c0 + c)) * HW_ + pixbase + p4];
        tile[c * 65 + p4]     = v.x;
        tile[c * 65 + p4 + 1] = v.y;
        tile[c * 65 + p4 + 2] = v.z;
        tile[c * 65 + p4 + 3] = v.w;
        float s = v.x + v.y + v.z + v.w;
        s += __shfl_down(s, 8, 16);
        s += __shfl_down(s, 4, 16);
        s += __shfl_down(s, 2, 16);
        s += __shfl_down(s, 1, 16);
        if ((t & 15) == 0) atomicAdd(&pooled[n * C_ + c0 + c], s * inv);
    }
    __syncthreads();
    int pix = t >> 2, part = t & 3;
    unsigned pk[8];
    #pragma unroll
    for (int i = 0; i < 16; i += 2) {
        ushort lo = f2bf(tile[(part * 16 + i) * 65 + pix]);
        ushort hi = f2bf(tile[(part * 16 + i + 1) * 65 + pix]);
        pk[i >> 1] = (unsigned)lo | ((unsigned)hi << 16);
    }
    ushort* dst = &x_t[((size_t)(n * HW_ + pixbase + pix)) * C_ + c0 + part * 16];
    *(uint4*)dst       = make_uint4(pk[0], pk[1], pk[2], pk[3]);
    *(uint4*)(dst + 8) = make_uint4(pk[4], pk[5], pk[6], pk[7]);
}

// ---- g[n,o] = relu(pooled[n,:] @ conv_w[o,:] + conv_b[o]) ----
__global__ __launch_bounds__(128) void g_kernel(const float* __restrict__ pooled,
                                                const float* __restrict__ conv_w,
                                                const float* __restrict__ conv_b,
                                                float* __restrict__ g) {
    int n = blockIdx.x, o = threadIdx.x;
    __shared__ float ps[C_];
    for (int c = threadIdx.x; c < C_; c += 128) ps[c] = pooled[n * C_ + c];
    __syncthreads();
    float acc = conv_b[o];
    for (int c = 0; c < C_; c++) acc += ps[c] * conv_w[o * C_ + c];
    g[n * CM_ + o] = fmaxf(acc, 0.f);
}

// ---- Wk in bf16 A-fragment layout: Wkf[(((n*9+kk)*16 + icb)*128 + oc)*8 + ci] ----
__global__ __launch_bounds__(256) void wk_frag(const float* __restrict__ g,
                                               const float* __restrict__ ck_w,
                                               const float* __restrict__ ck_b,
                                               const float* __restrict__ ckk_w,
                                               const float* __restrict__ ckk_b,
                                               ushort* __restrict__ Wkf) {
    int idx = blockIdx.x * 256 + threadIdx.x;   // exactly 4718592 total
    int ci = idx & 7, oc = (idx >> 3) & 127, icb = (idx >> 10) & 15, rest = idx >> 14;
    int kk = rest % 9, n = rest / 9;
    int ic = icb * 8 + ci;
    float ker = ck_w[kk] * g[n * CM_ + ic] + ck_b[kk];
    Wkf[idx] = f2bf(fmaxf(ckk_w[oc] * ker + ckk_b[oc], 0.f));
}

// ---- gemm_f: f_t[n][pix][cm] = relu(conv_w @ x + b), MFMA, K=512 ----
__global__ __launch_bounds__(256) void gemm_f(const ushort* __restrict__ x_t,
                                              const ushort* __restrict__ Acv,
                                              const float* __restrict__ conv_b,
                                              ushort* __restrict__ f_t) {
    int pixbase = blockIdx.x * 64, n = blockIdx.z;
    int t = threadIdx.x, wv = t >> 6, lane = t & 63, col = lane & 15, quad = lane >> 4;
    __shared__ ushort bsh[64 * 40];
    f32x4 z = {0.f, 0.f, 0.f, 0.f};
    f32x4 acc[2][4];
    #pragma unroll
    for (int mt = 0; mt < 2; mt++)
        #pragma unroll
        for (int ns = 0; ns < 4; ns++) acc[mt][ns] = z;
    int spix = t >> 2, sch = t & 3;
    const ushort* srcbase = &x_t[((size_t)(n * HW_ + pixbase + spix)) * C_ + sch * 8];
    for (int cb0 = 0; cb0 < 16; cb0++) {
        *(uint4*)&bsh[spix * 40 + sch * 8] = *(const uint4*)(srcbase + cb0 * 32);
        __syncthreads();
        bf16x8 a[2], b[4];
        #pragma unroll
        for (int mt = 0; mt < 2; mt++)
            a[mt] = *(const bf16x8*)&Acv[(((cb0 * 4 + quad) * CM_) + wv * 32 + mt * 16 + col) * 8];
        #pragma unroll
        for (int ns = 0; ns < 4; ns++)
            b[ns] = *(const bf16x8*)&bsh[(ns * 16 + col) * 40 + quad * 8];
        #pragma unroll
        for (int mt = 0; mt < 2; mt++)
            #pragma unroll
            for (int ns = 0; ns < 4; ns++)
                acc[mt][ns] = __builtin_amdgcn_mfma_f32_16x16x32_bf16(a[mt], b[ns], acc[mt][ns], 0, 0, 0);
        __syncthreads();
    }
    #pragma unroll
    for (int mt = 0; mt < 2; mt++) {
        int ocr = wv * 32 + mt * 16 + quad * 4;
        float b0 = conv_b[ocr], b1 = conv_b[ocr + 1], b2 = conv_b[ocr + 2], b3 = conv_b[ocr + 3];
        #pragma unroll
        for (int ns = 0; ns < 4; ns++) {
            int pix = pixbase + ns * 16 + col;
            ushort4 o;
            o.x = f2bf(fmaxf(acc[mt][ns][0] + b0, 0.f));
            o.y = f2bf(fmaxf(acc[mt][ns][1] + b1, 0.f));
            o.z = f2bf(fmaxf(acc[mt][ns][2] + b2, 0.f));
            o.w = f2bf(fmaxf(acc[mt][ns][3] + b3, 0.f));
            *(ushort4*)&f_t[((size_t)(n * HW_ + pix)) * CM_ + ocr] = o;
        }
    }
}

// ---- gemm_dyn: y_t[n][pix][oc] = adap_b + sum_{kk,ic} Wk*f(shifted), MFMA, K=9*128 ----
__global__ __launch_bounds__(256) void gemm_dyn(const ushort* __restrict__ f_t,
                                                const ushort* __restrict__ Wkf,
                                                const float* __restrict__ adap_b,
                                                ushort* __restrict__ y_t) {
    int pixbase = blockIdx.x * 64, n = blockIdx.z;
    int t = threadIdx.x, wv = t >> 6, lane = t & 63, col = lane & 15, quad = lane >> 4;
    int h_lo = pixbase / W_;
    __shared__ ushort fsh[232 * 40];   // 4 padded rows x 58 cols, 32 ic + pad 8
    int ldspix[4];
    #pragma unroll
    for (int ns = 0; ns < 4; ns++) {
        int pix = pixbase + ns * 16 + col;
        int h = pix / W_, w = pix - h * W_;
        ldspix[ns] = (h - h_lo) * 58 + w;
    }
    f32x4 acc[2][4];
    #pragma unroll
    for (int mt = 0; mt < 2; mt++) {
        int ocr = wv * 32 + mt * 16 + quad * 4;
        f32x4 ab = {adap_b[ocr], adap_b[ocr + 1], adap_b[ocr + 2], adap_b[ocr + 3]};
        #pragma unroll
        for (int ns = 0; ns < 4; ns++) acc[mt][ns] = ab;
    }
    for (int ic0 = 0; ic0 < CM_; ic0 += 32) {
        #pragma unroll
        for (int it = 0; it < 4; it++) {
            int idx = it * 256 + t;
            if (idx < 928) {
                int lp = idx >> 2, ch = idx & 3;
                int r = lp / 58, cw = lp - r * 58;
                int hp = h_lo + r;
                uint4 v = {0u, 0u, 0u, 0u};
                if (hp >= 1 && hp <= H_ && cw >= 1 && cw <= W_)
                    v = *(const uint4*)&f_t[((size_t)(n * HW_ + (hp - 1) * W_ + cw - 1)) * CM_ + ic0 + ch * 8];
                *(uint4*)&fsh[lp * 40 + ch * 8] = v;
            }
        }
        __syncthreads();
        #pragma unroll
        for (int dh = 0; dh < 3; dh++) {
            #pragma unroll
            for (int dw = 0; dw < 3; dw++) {
                int kk = dh * 3 + dw;
                bf16x8 a[2], b[4];
                #pragma unroll
                for (int mt = 0; mt < 2; mt++)
                    a[mt] = *(const bf16x8*)&Wkf[((((size_t)(n * 9 + kk) * 16) + (ic0 >> 3) + quad) * CM_ + wv * 32 + mt * 16 + col) * 8];
                #pragma unroll
                for (int ns = 0; ns < 4; ns++)
                    b[ns] = *(const bf16x8*)&fsh[(ldspix[ns] + dh * 58 + dw) * 40 + quad * 8];
                #pragma unroll
                for (int mt = 0; mt < 2; mt++)
                    #pragma unroll
                    for (int ns = 0; ns < 4; ns++)
                        acc[mt][ns] = __builtin_amdgcn_mfma_f32_16x16x32_bf16(a[mt], b[ns], acc[mt][ns], 0, 0, 0);
            }
        }
        __syncthreads();
    }
    #pragma unroll
    for (int mt = 0; mt < 2; mt++) {
        int ocr = wv * 32 + mt * 16 + quad * 4;
        #pragma unroll
        for (int ns = 0; ns < 4; ns++) {
            int pix = pixbase + ns * 16 + col;
            ushort4 o;
            o.x = f2bf(acc[mt][ns][0]);
            o.y = f2bf(acc[mt][ns][1]);
            o.z = f2bf(acc[mt][ns][2]);
            o.w = f2bf(acc[mt][ns][3]);
            *(ushort4*)&y_t[((size_t)(n * HW_ + pix)) * CM_ + ocr] = o;
        }
    }
}

// ---- gemm_fuse: out[n][p][pix] f32 = fuse_w @ y + fuse_b, MFMA, K=128 ----
__global__ __launch_bounds__(256) void gemm_fuse(const ushort* __restrict__ y_t,
                                                 const ushort* __restrict__ Afu,
                                                 const float* __restrict__ fuse_b,
                                                 float* __restrict__ out) {
    int pixbase = blockIdx.x * 64, pbase = blockIdx.y * 128, n = blockIdx.z;
    int t = threadIdx.x, wv = t >> 6, lane = t & 63, col = lane & 15, quad = lane >> 4;
    __shared__ ushort bsh[64 * 40];
    f32x4 z = {0.f, 0.f, 0.f, 0.f};
    f32x4 acc[2][4];
    #pragma unroll
    for (int mt = 0; mt < 2; mt++)
        #pragma unroll
        for (int ns = 0; ns < 4; ns++) acc[mt][ns] = z;
    int spix = t >> 2, sch = t & 3;
    const ushort* srcbase = &y_t[((size_t)(n * HW_ + pixbase + spix)) * CM_ + sch * 8];
    for (int cb0 = 0; cb0 < 4; cb0++) {
        *(uint4*)&bsh[spix * 40 + sch * 8] = *(const uint4*)(srcbase + cb0 * 32);
        __syncthreads();
        bf16x8 a[2], b[4];
        #pragma unroll
        for (int mt = 0; mt < 2; mt++)
            a[mt] = *(const bf16x8*)&Afu[(((cb0 * 4 + quad) * P_) + pbase + wv * 32 + mt * 16 + col) * 8];
        #pragma unroll
        for (int ns = 0; ns < 4; ns++)
            b[ns] = *(const bf16x8*)&bsh[(ns * 16 + col) * 40 + quad * 8];
        #pragma unroll
        for (int mt = 0; mt < 2; mt++)
            #pragma unroll
            for (int ns = 0; ns < 4; ns++)
                acc[mt][ns] = __builtin_amdgcn_mfma_f32_16x16x32_bf16(a[mt], b[ns], acc[mt][ns], 0, 0, 0);
        __syncthreads();
    }
    #pragma unroll
    for (int mt = 0; mt < 2; mt++) {
        int pr = pbase + wv * 32 + mt * 16 + quad * 4;
        #pragma unroll
        for (int ns = 0; ns < 4; ns++) {
            int pix = pixbase + ns * 16 + col;
            #pragma unroll
            for (int r = 0; r < 4; r++)
                out[((size_t)(n * P_ + pr + r)) * HW_ + pix] = acc[mt][ns][r] + fuse_b[pr + r];
        }
    }
}

extern "C" void kernel_launch(void* const* d_in, const int* in_sizes, int n_in,
                              void* d_out, int out_size, void* d_ws, size_t ws_size,
                              hipStream_t stream) {
    const float* x      = (const float*)d_in[0];
    const float* conv_w = (const float*)d_in[1];
    const float* conv_b = (const float*)d_in[2];
    const float* ck_w   = (const float*)d_in[3];
    const float* ck_b   = (const float*)d_in[4];
    const float* ckk_w  = (const float*)d_in[5];
    const float* ckk_b  = (const float*)d_in[6];
    const float* adap_b = (const float*)d_in[7];
    const float* fuse_w = (const float*)d_in[8];
    const float* fuse_b = (const float*)d_in[9];
    float* out = (float*)d_out;

    ushort* x_t = (ushort*)d_ws;                       // 51,380,224 ushorts
    ushort* y_t = x_t;                                 // alias: x_t dead after gemm_f
    ushort* f_t = x_t + (size_t)51380224;              // 12,845,056
    ushort* Wkf = f_t + (size_t)12845056;              // 4,718,592
    ushort* Acv = Wkf + (size_t)4718592;               // 65,536
    ushort* Afu = Acv + (size_t)65536;                 // 65,536
    float* pooled = (float*)(Afu + (size_t)65536);     // 16,384 floats
    float* g      = pooled + 16384;                    // 4,096 floats

    hipMemsetAsync(pooled, 0, 16384 * sizeof(float), stream);
    prep_w<<<512, 256, 0, stream>>>(conv_w, fuse_w, Acv, Afu);
    transpose_cast<<<dim3(49, 8, N_), 256, 0, stream>>>(x, x_t, pooled);
    g_kernel<<<N_, 128, 0, stream>>>(pooled, conv_w, conv_b, g);
    wk_frag<<<18432, 256, 0, stream>>>(g, ck_w, ck_b, ckk_w, ckk_b, Wkf);
    gemm_f<<<dim3(49, 1, N_), 256, 0, stream>>>(x_t, Acv, conv_b, f_t);
    gemm_dyn<<<dim3(49, 1, N_), 256, 0, stream>>>(f_t, Wkf, adap_b, y_t);
    gemm_fuse<<<dim3(49, 4, N_), 256, 0, stream>>>(y_t, Afu, fuse_b, out);
}